// Round 3
// baseline (7667.780 us; speedup 1.0000x reference)
//
#include <hip/hip_runtime.h>
#include <hip/hip_bf16.h>

using bf16 = __hip_bfloat16;
using bf16x8 = __attribute__((ext_vector_type(8))) short;   // 8 bf16 = 4 VGPRs
using f32x4  = __attribute__((ext_vector_type(4))) float;

#define S_LEN 256
#define NBATCH 32
#define HDIM 1024
#define NBLK 128

// ---------------------------------------------------------------------------
// Convert x (f32, [n][s][d]) -> xT (bf16, [s][n][d]).
// ---------------------------------------------------------------------------
__global__ __launch_bounds__(256) void convert_x(const float* __restrict__ x,
                                                 bf16* __restrict__ xT) {
    const int p = blockIdx.x;          // p = n*256 + s
    const int n = p >> 8;
    const int s = p & 255;
    const float* src = x + (size_t)p * 1024;
    bf16* dst = xT + (size_t)(s * NBATCH + n) * 1024;
#pragma unroll
    for (int j = 0; j < 4; j++) {
        const int d = threadIdx.x + j * 256;
        dst[d] = (bf16)src[d];
    }
}

// ---------------------------------------------------------------------------
// Convert + transpose: 8 matrices of 1024x1024, f32 in, bf16 out,
// out[g][c][r] = in[g][r][c]
// ---------------------------------------------------------------------------
__global__ __launch_bounds__(256) void convert_transpose_1024(const float* __restrict__ in,
                                                              bf16* __restrict__ out) {
    __shared__ float t[32][33];
    const int g  = blockIdx.z;
    const float* A = in  + (size_t)g * 1024 * 1024;
    bf16*        B = out + (size_t)g * 1024 * 1024;
    const int c0 = blockIdx.x * 32;
    const int r0 = blockIdx.y * 32;
    const int tx = threadIdx.x, ty = threadIdx.y;   // (32, 8)
#pragma unroll
    for (int j = 0; j < 32; j += 8)
        t[ty + j][tx] = A[(size_t)(r0 + ty + j) * 1024 + c0 + tx];
    __syncthreads();
#pragma unroll
    for (int j = 0; j < 32; j += 8)
        B[(size_t)(c0 + ty + j) * 1024 + r0 + tx] = (bf16)t[tx][ty + j];
}

// ---------------------------------------------------------------------------
// Persistent BiLSTM: 128 blocks x 1024 threads, all 256 steps in one launch.
// block = (dir = bi>>6, col0 = (bi&63)*16). 16 waves = 4 gates x 4 K-quarters
// of the fused K = 2048 (x-part 1024 | h-part 1024). LDS partial reduce, cell
// update by tid<512 with c,h carried in registers. Per-step grid barrier via
// per-block flags (device-scope atomics + __threadfence for cross-XCD).
// ---------------------------------------------------------------------------
__global__ __launch_bounds__(1024, 4) void lstm_persistent(
        const bf16* __restrict__ xT,
        const bf16* __restrict__ wihT,
        const bf16* __restrict__ whhT,
        const float* __restrict__ mask,
        const float* __restrict__ bias,
        bf16* __restrict__ hbuf,        // [2 parity][2 dir][32][1024] bf16
        unsigned* __restrict__ flags,   // [128] stride-16 words (64B apart)
        float* __restrict__ out) {
    __shared__ float part[16][32][16];  // 32 KB

    const int bi   = blockIdx.x;
    const int dir  = bi >> 6;
    const int col0 = (bi & 63) << 4;
    const int tid  = threadIdx.x;
    const int w    = tid >> 6;          // wave 0..15
    const int lane = tid & 63;
    const int r    = lane & 15;
    const int q    = lane >> 4;
    const int g    = w & 3;             // gate (f,i,o,c)
    const int kq   = w >> 2;            // K-quarter 0..3 (0,1 = x; 2,3 = h)

    // B row pointer: fixed for the whole sequence.
    const bf16* Bmat = (kq < 2 ? wihT : whhT)
                     + ((size_t)((dir * 4 + g) * 1024 + col0 + r)) * 1024
                     + (size_t)(kq & 1) * 512 + q * 8;

    // Update-thread state (tid < 512 owns cell (n = tid>>4, c = tid&15))
    const int un = tid >> 4;
    const int uc = tid & 15;
    float creg = 0.f, hreg = 0.f;
    float b0 = 0.f, b1 = 0.f, b2 = 0.f, b3 = 0.f;
    if (tid < 512) {
        const int gb = dir * 4 * 1024 + col0 + uc;
        b0 = bias[gb];
        b1 = bias[gb + 1024];
        b2 = bias[gb + 2048];
        b3 = bias[gb + 3072];
    }

    for (int t = 0; t < S_LEN; ++t) {
        const int s_idx = dir ? (S_LEN - 1 - t) : t;

        // ---- K-loop: 16 iters of K=32 over this wave's 512-wide K slice ----
        const bf16* A = (kq < 2)
            ? xT + (size_t)s_idx * NBATCH * HDIM
            : hbuf + ((size_t)((t & 1) * 2 + dir)) * NBATCH * HDIM;
        const bf16* Ar0 = A + (size_t)r * 1024 + (size_t)(kq & 1) * 512 + q * 8;
        const bf16* Ar1 = Ar0 + 16 * 1024;

        f32x4 acc0 = {}, acc1 = {};
#pragma unroll 4
        for (int kk = 0; kk < 512; kk += 32) {
            bf16x8 b  = *(const bf16x8*)(Bmat + kk);
            bf16x8 a0 = *(const bf16x8*)(Ar0 + kk);
            bf16x8 a1 = *(const bf16x8*)(Ar1 + kk);
            acc0 = __builtin_amdgcn_mfma_f32_16x16x32_bf16(a0, b, acc0, 0, 0, 0);
            acc1 = __builtin_amdgcn_mfma_f32_16x16x32_bf16(a1, b, acc1, 0, 0, 0);
        }
#pragma unroll
        for (int rr = 0; rr < 4; rr++) {
            part[w][q * 4 + rr][r]      = acc0[rr];
            part[w][16 + q * 4 + rr][r] = acc1[rr];
        }
        __syncthreads();

        // ---- cell update ----
        if (tid < 512) {
            const int n = un, c = uc;
            float pf = part[0][n][c] + part[4][n][c] + part[8][n][c]  + part[12][n][c] + b0;
            float pi = part[1][n][c] + part[5][n][c] + part[9][n][c]  + part[13][n][c] + b1;
            float po = part[2][n][c] + part[6][n][c] + part[10][n][c] + part[14][n][c] + b2;
            float pc = part[3][n][c] + part[7][n][c] + part[11][n][c] + part[15][n][c] + b3;
            const float f  = 1.f / (1.f + expf(-pf));
            const float i  = 1.f / (1.f + expf(-pi));
            const float o  = 1.f / (1.f + expf(-po));
            const float ct = tanhf(pc);
            creg = f * creg + i * ct;                 // c updated regardless of mask
            const float hnew = o * tanhf(creg);
            const float mt = mask[n * S_LEN + s_idx];
            const float hcar = (mt == 0.f) ? hreg : hnew;
            hreg = hcar;
            // publish h for next step's A-fragments (ping-pong parity t+1)
            hbuf[(((size_t)(((t + 1) & 1) * 2 + dir)) * NBATCH + n) * HDIM + col0 + c] = (bf16)hcar;
            out[((size_t)(n * S_LEN + s_idx)) * 2048 + dir * 1024 + col0 + c] = hcar * mt;
            if (t == S_LEN - 1)
                out[(size_t)NBATCH * S_LEN * 2048 + n * 2048 + dir * 1024 + col0 + c] = hcar;
        }

        // ---- grid barrier (release h writes, acquire others') ----
        __syncthreads();                 // drains vmcnt: block's stores are in L2
        if (tid == 0) {
            __threadfence();             // agent release: write back L2
            __hip_atomic_store(&flags[bi * 16], (unsigned)(t + 1),
                               __ATOMIC_RELEASE, __HIP_MEMORY_SCOPE_AGENT);
        }
        if (tid < NBLK) {
            int polls = 0;
            while (__hip_atomic_load(&flags[tid * 16], __ATOMIC_RELAXED,
                                     __HIP_MEMORY_SCOPE_AGENT) < (unsigned)(t + 1)) {
                if (++polls > (1 << 17)) break;      // safety valve: no hang
                __builtin_amdgcn_s_sleep(1);
            }
        }
        __syncthreads();
        if (tid == 0) __threadfence();   // agent acquire: invalidate L1/L2
        __syncthreads();
    }
}

// ---------------------------------------------------------------------------
// Workspace layout (bytes), total ~48.3 MB:
//   [0,          16777216)  xT    bf16 [256 s][32 n][1024 d]
//   [16777216,   33554432)  wihT  bf16 [8 g][1024 h][1024 d]
//   [33554432,   50331648)  whhT  bf16 [8 g][1024 h][1024 k]
//   [50331648,   50593792)  hbuf  bf16 [2 parity][2 dir][32][1024]
//   [50593792,   50601984)  flags u32  [128] stride 16 (64 B apart)
// ---------------------------------------------------------------------------
extern "C" void kernel_launch(void* const* d_in, const int* in_sizes, int n_in,
                              void* d_out, int out_size, void* d_ws, size_t ws_size,
                              hipStream_t stream) {
    const float* x    = (const float*)d_in[0];
    const float* mask = (const float*)d_in[1];
    const float* wih  = (const float*)d_in[2];
    const float* whh  = (const float*)d_in[3];
    const float* bias = (const float*)d_in[4];
    float* out = (float*)d_out;

    char* ws = (char*)d_ws;
    bf16*     xT    = (bf16*)(ws);
    bf16*     wihT  = (bf16*)(ws + 16777216);
    bf16*     whhT  = (bf16*)(ws + 33554432);
    bf16*     hbuf  = (bf16*)(ws + 50331648);
    unsigned* flags = (unsigned*)(ws + 50593792);

    // zero h (both parities) and barrier flags
    hipMemsetAsync(ws + 50331648, 0, 262144 + 8192, stream);

    convert_x<<<NBATCH * S_LEN, 256, 0, stream>>>(x, xT);
    dim3 tb(32, 8);
    convert_transpose_1024<<<dim3(32, 32, 8), tb, 0, stream>>>(wih, wihT);
    convert_transpose_1024<<<dim3(32, 32, 8), tb, 0, stream>>>(whh, whhT);

    lstm_persistent<<<NBLK, 1024, 0, stream>>>(xT, wihT, whhT, mask, bias,
                                               hbuf, flags, out);
}

// Round 4
// 5259.126 us; speedup vs baseline: 1.4580x; 1.4580x over previous
//
#include <hip/hip_runtime.h>
#include <hip/hip_bf16.h>

using bf16 = __hip_bfloat16;
using bf16x8 = __attribute__((ext_vector_type(8))) short;   // 8 bf16 = 4 VGPRs
using f32x4  = __attribute__((ext_vector_type(4))) float;

#define S_LEN 256
#define NBATCH 32
#define HDIM 1024
#define NBLK 256

// ---------------------------------------------------------------------------
// Convert x (f32, [n][s][d]) -> xT (bf16, [s][n][d]).
// ---------------------------------------------------------------------------
__global__ __launch_bounds__(256) void convert_x(const float* __restrict__ x,
                                                 bf16* __restrict__ xT) {
    const int p = blockIdx.x;          // p = n*256 + s
    const int n = p >> 8;
    const int s = p & 255;
    const float* src = x + (size_t)p * 1024;
    bf16* dst = xT + (size_t)(s * NBATCH + n) * 1024;
#pragma unroll
    for (int j = 0; j < 4; j++) {
        const int d = threadIdx.x + j * 256;
        dst[d] = (bf16)src[d];
    }
}

// ---------------------------------------------------------------------------
// Convert + transpose: 8 matrices of 1024x1024, f32 in, bf16 out,
// out[g][c][r] = in[g][r][c]
// ---------------------------------------------------------------------------
__global__ __launch_bounds__(256) void convert_transpose_1024(const float* __restrict__ in,
                                                              bf16* __restrict__ out) {
    __shared__ float t[32][33];
    const int g  = blockIdx.z;
    const float* A = in  + (size_t)g * 1024 * 1024;
    bf16*        B = out + (size_t)g * 1024 * 1024;
    const int c0 = blockIdx.x * 32;
    const int r0 = blockIdx.y * 32;
    const int tx = threadIdx.x, ty = threadIdx.y;   // (32, 8)
#pragma unroll
    for (int j = 0; j < 32; j += 8)
        t[ty + j][tx] = A[(size_t)(r0 + ty + j) * 1024 + c0 + tx];
    __syncthreads();
#pragma unroll
    for (int j = 0; j < 32; j += 8)
        B[(size_t)(c0 + ty + j) * 1024 + r0 + tx] = (bf16)t[tx][ty + j];
}

// ---------------------------------------------------------------------------
// Persistent BiLSTM, weights pinned in REGISTERS (persistent-RNN style).
// 256 blocks x 1024 threads, 1 block/CU. Block = (dir = bi>>7, 8 cols).
// 16 waves = 8 K-slices (kq: 0-3 = x-part, 4-7 = h-part; 256 K each)
//          x 2 M-halves (16 batch rows each).
// Each wave holds B-frags for BOTH gate-pairs in regs: 2 gp x 8 iters x 16B
// = 64 VGPRs, loaded once. Packed B-frag: D cols 0-7 = gate gp*2 cols,
// cols 8-15 = gate gp*2+1 cols -> 100% MFMA occupancy, A loaded once per
// (kq,mh). Partials -> LDS (stride-40 pad) -> 256 update threads with c,h
// in registers. Per-step grid barrier via per-block flags.
// ---------------------------------------------------------------------------
__global__ __launch_bounds__(1024) void lstm_persistent(
        const bf16* __restrict__ xT,
        const bf16* __restrict__ wihT,
        const bf16* __restrict__ whhT,
        const float* __restrict__ mask,
        const float* __restrict__ bias,
        bf16* __restrict__ hbuf,        // [2 parity][2 dir][32][1024] bf16
        unsigned* __restrict__ flags,   // [256] stride-16 words
        float* __restrict__ out) {
    __shared__ float part[16 * 16 * 40];   // [slab=kq*2+mh][m 16][40] = 40 KB

    const int bi   = blockIdx.x;
    const int dir  = bi >> 7;
    const int col0 = (bi & 127) << 3;
    const int tid  = threadIdx.x;
    const int w    = tid >> 6;          // wave 0..15
    const int lane = tid & 63;
    const int r    = lane & 15;
    const int q    = lane >> 4;
    const int kq   = w & 7;             // K-slice (0-3: x | 4-7: h)
    const int mh   = w >> 3;            // M-half

    // ---- one-time: pin B fragments in registers for all 256 steps ----
    bf16x8 bfr[2][8];
    {
        const bf16* M = (kq < 4) ? wihT : whhT;
        const int krel = (kq & 3) * 256 + q * 8;
#pragma unroll
        for (int gp = 0; gp < 2; gp++) {
            const int gate = gp * 2 + (r >> 3);
            const size_t row = (size_t)((dir * 4 + gate) * 1024 + col0 + (r & 7));
#pragma unroll
            for (int it = 0; it < 8; it++)
                bfr[gp][it] = *(const bf16x8*)(M + row * 1024 + krel + it * 32);
        }
    }

    // ---- update-thread state (tid < 256 owns cell (n = tid>>3, c = tid&7))
    const int un = tid >> 3;
    const int uc = tid & 7;
    float creg = 0.f, hreg = 0.f;
    float b0 = 0.f, b1 = 0.f, b2 = 0.f, b3 = 0.f;
    if (tid < 256) {
        const int gb = (dir * 4) * 1024 + col0 + uc;
        b0 = bias[gb];
        b1 = bias[gb + 1024];
        b2 = bias[gb + 2048];
        b3 = bias[gb + 3072];
    }

    for (int t = 0; t < S_LEN; ++t) {
        const int s_idx = dir ? (S_LEN - 1 - t) : t;

        // ---- MFMA phase: 8 iters x 2 MFMAs, A from global, B from regs ----
        const bf16* A = (kq < 4)
            ? xT + (size_t)s_idx * NBATCH * HDIM
            : hbuf + (size_t)((t & 1) * 2 + dir) * NBATCH * HDIM;
        const bf16* Ap = A + (size_t)(mh * 16 + r) * 1024 + (kq & 3) * 256 + q * 8;

        f32x4 acc0 = {}, acc1 = {};
#pragma unroll
        for (int it = 0; it < 8; it++) {
            bf16x8 a = *(const bf16x8*)(Ap + it * 32);
            acc0 = __builtin_amdgcn_mfma_f32_16x16x32_bf16(a, bfr[0][it], acc0, 0, 0, 0);
            acc1 = __builtin_amdgcn_mfma_f32_16x16x32_bf16(a, bfr[1][it], acc1, 0, 0, 0);
        }
        const int pbase = ((kq * 2 + mh) * 16) * 40;
#pragma unroll
        for (int rr = 0; rr < 4; rr++) {
            part[pbase + (q * 4 + rr) * 40 + r]      = acc0[rr];   // gates 0,1
            part[pbase + (q * 4 + rr) * 40 + 16 + r] = acc1[rr];   // gates 2,3
        }
        __syncthreads();

        // ---- cell update ----
        if (tid < 256) {
            const int sb = un >> 4;       // which M-half
            const int m  = un & 15;
            float pf = b0, pi = b1, po = b2, pc = b3;
#pragma unroll
            for (int k = 0; k < 8; k++) {
                const int base = ((k * 2 + sb) * 16 + m) * 40;
                pf += part[base + uc];
                pi += part[base + 8 + uc];
                po += part[base + 16 + uc];
                pc += part[base + 24 + uc];
            }
            const float f  = 1.f / (1.f + expf(-pf));
            const float i  = 1.f / (1.f + expf(-pi));
            const float o  = 1.f / (1.f + expf(-po));
            const float ct = tanhf(pc);
            creg = f * creg + i * ct;                 // c updated regardless of mask
            const float hnew = o * tanhf(creg);
            const float mt = mask[un * S_LEN + s_idx];
            const float hcar = (mt == 0.f) ? hreg : hnew;
            hreg = hcar;
            hbuf[((size_t)(((t + 1) & 1) * 2 + dir) * NBATCH + un) * HDIM + col0 + uc] = (bf16)hcar;
            out[((size_t)(un * S_LEN + s_idx)) * 2048 + dir * 1024 + col0 + uc] = hcar * mt;
            if (t == S_LEN - 1)
                out[(size_t)NBATCH * S_LEN * 2048 + un * 2048 + dir * 1024 + col0 + uc] = hcar;
        }

        // ---- grid barrier ----
        __syncthreads();
        if (tid == 0) {
            __threadfence();             // agent release
            __hip_atomic_store(&flags[bi * 16], (unsigned)(t + 1),
                               __ATOMIC_RELEASE, __HIP_MEMORY_SCOPE_AGENT);
        }
        if (tid < NBLK) {
            int polls = 0;
            while (__hip_atomic_load(&flags[tid * 16], __ATOMIC_RELAXED,
                                     __HIP_MEMORY_SCOPE_AGENT) < (unsigned)(t + 1)) {
                if (++polls > (1 << 17)) break;      // safety valve: no hang
                __builtin_amdgcn_s_sleep(1);
            }
        }
        __syncthreads();
        if (tid == 0) __threadfence();   // agent acquire
        __syncthreads();
    }
}

// ---------------------------------------------------------------------------
// Workspace layout (bytes), total ~48.3 MB:
//   [0,          16777216)  xT    bf16 [256 s][32 n][1024 d]
//   [16777216,   33554432)  wihT  bf16 [8 g][1024 h][1024 d]
//   [33554432,   50331648)  whhT  bf16 [8 g][1024 h][1024 k]
//   [50331648,   50593792)  hbuf  bf16 [2 parity][2 dir][32][1024]
//   [50593792,   50610176)  flags u32  [256] stride 16
// ---------------------------------------------------------------------------
extern "C" void kernel_launch(void* const* d_in, const int* in_sizes, int n_in,
                              void* d_out, int out_size, void* d_ws, size_t ws_size,
                              hipStream_t stream) {
    const float* x    = (const float*)d_in[0];
    const float* mask = (const float*)d_in[1];
    const float* wih  = (const float*)d_in[2];
    const float* whh  = (const float*)d_in[3];
    const float* bias = (const float*)d_in[4];
    float* out = (float*)d_out;

    char* ws = (char*)d_ws;
    bf16*     xT    = (bf16*)(ws);
    bf16*     wihT  = (bf16*)(ws + 16777216);
    bf16*     whhT  = (bf16*)(ws + 33554432);
    bf16*     hbuf  = (bf16*)(ws + 50331648);
    unsigned* flags = (unsigned*)(ws + 50593792);

    // zero h (both parities) and barrier flags
    hipMemsetAsync(ws + 50331648, 0, 262144 + 16384, stream);

    convert_x<<<NBATCH * S_LEN, 256, 0, stream>>>(x, xT);
    dim3 tb(32, 8);
    convert_transpose_1024<<<dim3(32, 32, 8), tb, 0, stream>>>(wih, wihT);
    convert_transpose_1024<<<dim3(32, 32, 8), tb, 0, stream>>>(whh, whhT);

    lstm_persistent<<<NBLK, 1024, 0, stream>>>(xT, wihT, whhT, mask, bias,
                                               hbuf, flags, out);
}

// Round 5
// 4411.141 us; speedup vs baseline: 1.7383x; 1.1922x over previous
//
#include <hip/hip_runtime.h>
#include <hip/hip_bf16.h>

using bf16 = __hip_bfloat16;
using bf16x8 = __attribute__((ext_vector_type(8))) short;   // 8 bf16 = 4 VGPRs
using f32x4  = __attribute__((ext_vector_type(4))) float;

#define S_LEN 256
#define NBATCH 32
#define HDIM 1024
#define NBLK 256

// ---------------------------------------------------------------------------
// Convert x (f32, [n][s][d]) -> xT (bf16, [s][n][d]).
// ---------------------------------------------------------------------------
__global__ __launch_bounds__(256) void convert_x(const float* __restrict__ x,
                                                 bf16* __restrict__ xT) {
    const int p = blockIdx.x;          // p = n*256 + s
    const int n = p >> 8;
    const int s = p & 255;
    const float* src = x + (size_t)p * 1024;
    bf16* dst = xT + (size_t)(s * NBATCH + n) * 1024;
#pragma unroll
    for (int j = 0; j < 4; j++) {
        const int d = threadIdx.x + j * 256;
        dst[d] = (bf16)src[d];
    }
}

// ---------------------------------------------------------------------------
// Convert + transpose: 8 matrices of 1024x1024, f32 in, bf16 out,
// out[g][c][r] = in[g][r][c]
// ---------------------------------------------------------------------------
__global__ __launch_bounds__(256) void convert_transpose_1024(const float* __restrict__ in,
                                                              bf16* __restrict__ out) {
    __shared__ float t[32][33];
    const int g  = blockIdx.z;
    const float* A = in  + (size_t)g * 1024 * 1024;
    bf16*        B = out + (size_t)g * 1024 * 1024;
    const int c0 = blockIdx.x * 32;
    const int r0 = blockIdx.y * 32;
    const int tx = threadIdx.x, ty = threadIdx.y;   // (32, 8)
#pragma unroll
    for (int j = 0; j < 32; j += 8)
        t[ty + j][tx] = A[(size_t)(r0 + ty + j) * 1024 + c0 + tx];
    __syncthreads();
#pragma unroll
    for (int j = 0; j < 32; j += 8)
        B[(size_t)(c0 + ty + j) * 1024 + r0 + tx] = (bf16)t[tx][ty + j];
}

// ---------------------------------------------------------------------------
// Persistent BiLSTM, fence-free. 256 blocks x 1024 threads, 1 block/CU.
// Block = (dir, 8 cols). Wave w (0..15) owns K-slice [w*64, w*64+64) of BOTH
// Wih and Whh (pinned: 2 gate-pairs x 2 iters x 2 mats = 32 VGPRs/lane).
// Per step: x(t+1) MFMAs overlap the flag poll (waves 14,15 spin); h(t) read
// via cache-bypassing agent atomics accumulates into the held x(t) partials;
// combined partials -> 64KB XOR-swizzled LDS -> 256 update threads (c,h in
// regs) -> h(t+1) published as packed-u32 agent atomic stores; flag RELEASE.
// No __threadfence: nothing dirty/stale is ever cached for h.
// ---------------------------------------------------------------------------
__global__ __launch_bounds__(1024) void lstm_persistent(
        const bf16* __restrict__ xT,
        const bf16* __restrict__ wihT,
        const bf16* __restrict__ whhT,
        const float* __restrict__ mask,
        const float* __restrict__ bias,
        unsigned* __restrict__ hbuf,    // [2 par][2 dir][32 n][512] u32 (bf16 pairs)
        unsigned* __restrict__ flags,   // [256] stride-16 words
        float* __restrict__ out) {
    __shared__ float part[16 * 1024];   // 64 KB: slab w = [32 rows][32 cols] swizzled

    const int bi   = blockIdx.x;
    const int dir  = bi >> 7;
    const int col0 = (bi & 127) << 3;
    const int tid  = threadIdx.x;
    const int w    = tid >> 6;
    const int lane = tid & 63;
    const int r    = lane & 15;
    const int q    = lane >> 4;
    const int kbase = w * 64 + q * 8;   // this wave's K-slice origin (+quad)

    // ---- pin weights: B-frags for both matrices, both gate-pairs ----
    bf16x8 bx[2][2], bh[2][2];
#pragma unroll
    for (int gp = 0; gp < 2; gp++) {
        const int gate = gp * 2 + (r >> 3);
        const size_t rowoff = ((size_t)((dir * 4 + gate) * 1024 + col0 + (r & 7))) * 1024 + kbase;
#pragma unroll
        for (int it = 0; it < 2; it++) {
            bx[gp][it] = *(const bf16x8*)(wihT + rowoff + it * 32);
            bh[gp][it] = *(const bf16x8*)(whhT + rowoff + it * 32);
        }
    }

    // ---- update-thread state (tid<256 owns (n = tid>>3, c = tid&7)) ----
    const int un = tid >> 3;
    const int uc = tid & 7;
    float creg = 0.f, hreg = 0.f;
    float b0 = 0.f, b1 = 0.f, b2 = 0.f, b3 = 0.f;
    if (tid < 256) {
        const int gb = (dir * 4) * 1024 + col0 + uc;
        b0 = bias[gb];
        b1 = bias[gb + 1024];
        b2 = bias[gb + 2048];
        b3 = bias[gb + 3072];
    }

    const f32x4 vzero = {0.f, 0.f, 0.f, 0.f};
    f32x4 accA[2][2], accB[2][2];
#pragma unroll
    for (int mh = 0; mh < 2; mh++) { accB[mh][0] = vzero; accB[mh][1] = vzero; }

    // ---- prologue: accA = x(0) partials ----
    {
        const int s_id = dir ? (S_LEN - 1) : 0;
        const bf16* Ax = xT + (size_t)s_id * NBATCH * HDIM + kbase;
#pragma unroll
        for (int mh = 0; mh < 2; mh++) {
            accA[mh][0] = vzero; accA[mh][1] = vzero;
#pragma unroll
            for (int it = 0; it < 2; it++) {
                bf16x8 a = *(const bf16x8*)(Ax + (size_t)(mh * 16 + r) * HDIM + it * 32);
                accA[mh][0] = __builtin_amdgcn_mfma_f32_16x16x32_bf16(a, bx[0][it], accA[mh][0], 0, 0, 0);
                accA[mh][1] = __builtin_amdgcn_mfma_f32_16x16x32_bf16(a, bx[1][it], accA[mh][1], 0, 0, 0);
            }
        }
    }

    for (int t = 0; t < S_LEN; ++t) {
        // ---- poll (waves 14,15): all same-dir blocks published step t ----
        if (tid >= 896) {
            const unsigned* fp = flags + ((dir << 7) + (tid & 127)) * 16;
            int polls = 0;
            while (__hip_atomic_load(fp, __ATOMIC_RELAXED, __HIP_MEMORY_SCOPE_AGENT)
                   < (unsigned)t) {
                if (++polls > (1 << 16)) break;      // safety valve
                __builtin_amdgcn_s_sleep(1);
            }
        }
        // ---- overlap: x(t+1) -> accB (no cross-block dependency) ----
        if (t + 1 < S_LEN) {
            const int s_id = dir ? (S_LEN - 2 - t) : (t + 1);
            const bf16* Ax = xT + (size_t)s_id * NBATCH * HDIM + kbase;
#pragma unroll
            for (int mh = 0; mh < 2; mh++) {
                accB[mh][0] = vzero; accB[mh][1] = vzero;
#pragma unroll
                for (int it = 0; it < 2; it++) {
                    bf16x8 a = *(const bf16x8*)(Ax + (size_t)(mh * 16 + r) * HDIM + it * 32);
                    accB[mh][0] = __builtin_amdgcn_mfma_f32_16x16x32_bf16(a, bx[0][it], accB[mh][0], 0, 0, 0);
                    accB[mh][1] = __builtin_amdgcn_mfma_f32_16x16x32_bf16(a, bx[1][it], accB[mh][1], 0, 0, 0);
                }
            }
        }
        __syncthreads();   // h(t) now globally visible to every wave

        // ---- h(t) @ Whh accumulated into accA (cache-bypass loads) ----
        {
            const unsigned* Hp = hbuf + ((size_t)((t & 1) * 2 + dir) * NBATCH) * 512 + (kbase >> 1);
#pragma unroll
            for (int mh = 0; mh < 2; mh++) {
                const unsigned* hrow = Hp + (mh * 16 + r) * 512;
#pragma unroll
                for (int it = 0; it < 2; it++) {
                    union { unsigned u[4]; bf16x8 v; } av;
#pragma unroll
                    for (int j = 0; j < 4; j++)
                        av.u[j] = __hip_atomic_load(hrow + it * 16 + j,
                                                    __ATOMIC_RELAXED, __HIP_MEMORY_SCOPE_AGENT);
                    accA[mh][0] = __builtin_amdgcn_mfma_f32_16x16x32_bf16(av.v, bh[0][it], accA[mh][0], 0, 0, 0);
                    accA[mh][1] = __builtin_amdgcn_mfma_f32_16x16x32_bf16(av.v, bh[1][it], accA[mh][1], 0, 0, 0);
                }
            }
        }
        // ---- write combined partials to LDS (XOR swizzle: 2-way max) ----
        {
            float* slab = part + w * 1024;
#pragma unroll
            for (int mh = 0; mh < 2; mh++)
#pragma unroll
                for (int gp = 0; gp < 2; gp++)
#pragma unroll
                    for (int rr = 0; rr < 4; rr++) {
                        const int row = mh * 16 + q * 4 + rr;
                        const int pc = (gp * 16 + r) ^ (((row >> 2) & 3) * 8);
                        slab[row * 32 + pc] = accA[mh][gp][rr];
                    }
        }
#pragma unroll
        for (int mh = 0; mh < 2; mh++) { accA[mh][0] = accB[mh][0]; accA[mh][1] = accB[mh][1]; }
        __syncthreads();

        // ---- cell update ----
        if (tid < 256) {
            const int swz = ((un >> 2) & 3) * 8;
            float pf = b0, pi = b1, po = b2, pg = b3;
#pragma unroll
            for (int ww = 0; ww < 16; ww++) {
                const float* rowp = part + ww * 1024 + un * 32;
                pf += rowp[(0  ^ swz) + uc];
                pi += rowp[(8  ^ swz) + uc];
                po += rowp[(16 ^ swz) + uc];
                pg += rowp[(24 ^ swz) + uc];
            }
            const float f  = 1.f / (1.f + expf(-pf));
            const float i  = 1.f / (1.f + expf(-pi));
            const float o  = 1.f / (1.f + expf(-po));
            const float ct = tanhf(pg);
            creg = f * creg + i * ct;                 // c updated regardless of mask
            const float hnew = o * tanhf(creg);
            const int s_idx = dir ? (S_LEN - 1 - t) : t;
            const float mt = mask[un * S_LEN + s_idx];
            const float hcar = (mt == 0.f) ? hreg : hnew;
            hreg = hcar;
            // publish h(t+1): pack col-pair, agent-scope write-through store
            union { bf16 b; unsigned short u; } cv;
            cv.b = (bf16)hcar;
            const unsigned mine = cv.u;
            const unsigned other = (unsigned)__shfl_xor((int)mine, 1);
            if ((uc & 1) == 0) {
                unsigned* dst = hbuf + ((size_t)(((t + 1) & 1) * 2 + dir) * NBATCH + un) * 512
                              + ((col0 + uc) >> 1);
                __hip_atomic_store(dst, mine | (other << 16),
                                   __ATOMIC_RELAXED, __HIP_MEMORY_SCOPE_AGENT);
            }
            out[((size_t)(un * S_LEN + s_idx)) * 2048 + dir * 1024 + col0 + uc] = hcar * mt;
            if (t == S_LEN - 1)
                out[(size_t)NBATCH * S_LEN * 2048 + un * 2048 + dir * 1024 + col0 + uc] = hcar;
        }
        __syncthreads();   // drains every wave's stores (vmcnt) before publish
        if (tid == 0)
            __hip_atomic_store(&flags[bi * 16], (unsigned)(t + 1),
                               __ATOMIC_RELEASE, __HIP_MEMORY_SCOPE_AGENT);
    }
}

// ---------------------------------------------------------------------------
// Workspace layout (bytes), total ~48.3 MB:
//   [0,          16777216)  xT    bf16 [256 s][32 n][1024 d]
//   [16777216,   33554432)  wihT  bf16 [8 g][1024 h][1024 d]
//   [33554432,   50331648)  whhT  bf16 [8 g][1024 h][1024 k]
//   [50331648,   50593792)  hbuf  bf16 [2 parity][2 dir][32][1024] (u32 access)
//   [50593792,   50610176)  flags u32  [256] stride 16
// ---------------------------------------------------------------------------
extern "C" void kernel_launch(void* const* d_in, const int* in_sizes, int n_in,
                              void* d_out, int out_size, void* d_ws, size_t ws_size,
                              hipStream_t stream) {
    const float* x    = (const float*)d_in[0];
    const float* mask = (const float*)d_in[1];
    const float* wih  = (const float*)d_in[2];
    const float* whh  = (const float*)d_in[3];
    const float* bias = (const float*)d_in[4];
    float* out = (float*)d_out;

    char* ws = (char*)d_ws;
    bf16*     xT    = (bf16*)(ws);
    bf16*     wihT  = (bf16*)(ws + 16777216);
    bf16*     whhT  = (bf16*)(ws + 33554432);
    unsigned* hbuf  = (unsigned*)(ws + 50331648);
    unsigned* flags = (unsigned*)(ws + 50593792);

    // zero h (both parities) and barrier flags (ws is re-poisoned every call)
    hipMemsetAsync(ws + 50331648, 0, 262144 + 16384, stream);

    convert_x<<<NBATCH * S_LEN, 256, 0, stream>>>(x, xT);
    dim3 tb(32, 8);
    convert_transpose_1024<<<dim3(32, 32, 8), tb, 0, stream>>>(wih, wihT);
    convert_transpose_1024<<<dim3(32, 32, 8), tb, 0, stream>>>(whh, whhT);

    lstm_persistent<<<NBLK, 1024, 0, stream>>>(xT, wihT, whhT, mask, bias,
                                               hbuf, flags, out);
}

// Round 6
// 3049.662 us; speedup vs baseline: 2.5143x; 1.4464x over previous
//
#include <hip/hip_runtime.h>
#include <hip/hip_bf16.h>

using bf16 = __hip_bfloat16;
using bf16x8 = __attribute__((ext_vector_type(8))) short;   // 8 bf16 = 4 VGPRs
using f32x4  = __attribute__((ext_vector_type(4))) float;

#define S_LEN 256
#define NBATCH 32
#define HDIM 1024
#define NBLK 256

// ---------------------------------------------------------------------------
// Convert x (f32, [n][s][d]) -> xT (bf16, [s][n][d]).
// ---------------------------------------------------------------------------
__global__ __launch_bounds__(256) void convert_x(const float* __restrict__ x,
                                                 bf16* __restrict__ xT) {
    const int p = blockIdx.x;          // p = n*256 + s
    const int n = p >> 8;
    const int s = p & 255;
    const float* src = x + (size_t)p * 1024;
    bf16* dst = xT + (size_t)(s * NBATCH + n) * 1024;
#pragma unroll
    for (int j = 0; j < 4; j++) {
        const int d = threadIdx.x + j * 256;
        dst[d] = (bf16)src[d];
    }
}

// ---------------------------------------------------------------------------
// Convert + transpose: 8 matrices of 1024x1024, f32 in, bf16 out,
// out[g][c][r] = in[g][r][c]
// ---------------------------------------------------------------------------
__global__ __launch_bounds__(256) void convert_transpose_1024(const float* __restrict__ in,
                                                              bf16* __restrict__ out) {
    __shared__ float t[32][33];
    const int g  = blockIdx.z;
    const float* A = in  + (size_t)g * 1024 * 1024;
    bf16*        B = out + (size_t)g * 1024 * 1024;
    const int c0 = blockIdx.x * 32;
    const int r0 = blockIdx.y * 32;
    const int tx = threadIdx.x, ty = threadIdx.y;   // (32, 8)
#pragma unroll
    for (int j = 0; j < 32; j += 8)
        t[ty + j][tx] = A[(size_t)(r0 + ty + j) * 1024 + c0 + tx];
    __syncthreads();
#pragma unroll
    for (int j = 0; j < 32; j += 8)
        B[(size_t)(c0 + ty + j) * 1024 + r0 + tx] = (bf16)t[tx][ty + j];
}

// ---------------------------------------------------------------------------
// Persistent BiLSTM, fence-free AND wbl2-free. 256 blocks x 1024 thr.
// Block = (dir, 8 cols). Wave w owns K-slice [w*64,(w+1)*64) of Wih+Whh
// (pinned in regs). Per step: x(t+1) MFMAs overlap flag poll (waves 14,15);
// h(t) via sc1 cache-bypass atomic loads -> 8 MFMAs into held x(t) partials;
// partials -> 64KB XOR-swizzled LDS (<=2-way both ways) -> 256 update
// threads (c,h in regs) -> h(t+1) published as packed-u32 sc1 stores ->
// RELAXED flag publish (h stores vmcnt-acked at L3 by __syncthreads, so no
// release/wbl2 needed; out[] only read at kernel end) -> out stores last.
// ---------------------------------------------------------------------------
__global__ __launch_bounds__(1024) void lstm_persistent(
        const bf16* __restrict__ xT,
        const bf16* __restrict__ wihT,
        const bf16* __restrict__ whhT,
        const float* __restrict__ mask,
        const float* __restrict__ bias,
        unsigned* __restrict__ hbuf,    // [2 par][2 dir][32 n][512] u32 (bf16 pairs)
        unsigned* __restrict__ flags,   // [256] stride-16 words
        float* __restrict__ out) {
    __shared__ float part[16 * 1024];   // 64 KB: slab w = [32 rows][32 cols] swizzled

    const int bi   = blockIdx.x;
    const int dir  = bi >> 7;
    const int col0 = (bi & 127) << 3;
    const int tid  = threadIdx.x;
    const int w    = tid >> 6;
    const int lane = tid & 63;
    const int r    = lane & 15;
    const int q    = lane >> 4;
    const int kbase = w * 64 + q * 8;   // this wave's K-slice origin (+quad)

    // ---- pin weights: B-frags for both matrices, both gate-pairs ----
    bf16x8 bx[2][2], bh[2][2];
#pragma unroll
    for (int gp = 0; gp < 2; gp++) {
        const int gate = gp * 2 + (r >> 3);
        const size_t rowoff = ((size_t)((dir * 4 + gate) * 1024 + col0 + (r & 7))) * 1024 + kbase;
#pragma unroll
        for (int it = 0; it < 2; it++) {
            bx[gp][it] = *(const bf16x8*)(wihT + rowoff + it * 32);
            bh[gp][it] = *(const bf16x8*)(whhT + rowoff + it * 32);
        }
    }

    // ---- update-thread state (tid<256 owns (n = tid>>3, c = tid&7)) ----
    const int un = tid >> 3;
    const int uc = tid & 7;
    float creg = 0.f, hreg = 0.f;
    float b0 = 0.f, b1 = 0.f, b2 = 0.f, b3 = 0.f;
    if (tid < 256) {
        const int gb = (dir * 4) * 1024 + col0 + uc;
        b0 = bias[gb];
        b1 = bias[gb + 1024];
        b2 = bias[gb + 2048];
        b3 = bias[gb + 3072];
    }
    // update-read swizzle constants (row = un): ((un>>2)&3)*8 ^ ((un&1)*4)
    const int rswz = ((((un >> 2) & 3) * 8) ^ ((un & 1) * 4));

    const f32x4 vzero = {0.f, 0.f, 0.f, 0.f};
    f32x4 accA[2][2], accB[2][2];
#pragma unroll
    for (int mh = 0; mh < 2; mh++) { accB[mh][0] = vzero; accB[mh][1] = vzero; }

    // ---- prologue: accA = x(0) partials ----
    {
        const int s_id = dir ? (S_LEN - 1) : 0;
        const bf16* Ax = xT + (size_t)s_id * NBATCH * HDIM + kbase;
#pragma unroll
        for (int mh = 0; mh < 2; mh++) {
            accA[mh][0] = vzero; accA[mh][1] = vzero;
#pragma unroll
            for (int it = 0; it < 2; it++) {
                bf16x8 a = *(const bf16x8*)(Ax + (size_t)(mh * 16 + r) * HDIM + it * 32);
                accA[mh][0] = __builtin_amdgcn_mfma_f32_16x16x32_bf16(a, bx[0][it], accA[mh][0], 0, 0, 0);
                accA[mh][1] = __builtin_amdgcn_mfma_f32_16x16x32_bf16(a, bx[1][it], accA[mh][1], 0, 0, 0);
            }
        }
    }

    for (int t = 0; t < S_LEN; ++t) {
        const int s_idx = dir ? (S_LEN - 1 - t) : t;

        // ---- poll (waves 14,15): all same-dir blocks published step t ----
        if (tid >= 896) {
            const unsigned* fp = flags + ((dir << 7) + (tid & 127)) * 16;
            int polls = 0;
            while (__hip_atomic_load(fp, __ATOMIC_RELAXED, __HIP_MEMORY_SCOPE_AGENT)
                   < (unsigned)t) {
                if (++polls > (1 << 16)) break;      // safety valve
                __builtin_amdgcn_s_sleep(1);
            }
        }
        // ---- overlap: x(t+1) -> accB (no cross-block dependency) ----
        if (t + 1 < S_LEN) {
            const int s_id = dir ? (S_LEN - 2 - t) : (t + 1);
            const bf16* Ax = xT + (size_t)s_id * NBATCH * HDIM + kbase;
#pragma unroll
            for (int mh = 0; mh < 2; mh++) {
                accB[mh][0] = vzero; accB[mh][1] = vzero;
#pragma unroll
                for (int it = 0; it < 2; it++) {
                    bf16x8 a = *(const bf16x8*)(Ax + (size_t)(mh * 16 + r) * HDIM + it * 32);
                    accB[mh][0] = __builtin_amdgcn_mfma_f32_16x16x32_bf16(a, bx[0][it], accB[mh][0], 0, 0, 0);
                    accB[mh][1] = __builtin_amdgcn_mfma_f32_16x16x32_bf16(a, bx[1][it], accB[mh][1], 0, 0, 0);
                }
            }
        }
        __syncthreads();   // h(t) now globally visible to every wave

        // ---- h(t) @ Whh accumulated into accA (cache-bypass loads) ----
        {
            const unsigned* Hp = hbuf + ((size_t)((t & 1) * 2 + dir) * NBATCH) * 512 + (kbase >> 1);
#pragma unroll
            for (int mh = 0; mh < 2; mh++) {
                const unsigned* hrow = Hp + (mh * 16 + r) * 512;
#pragma unroll
                for (int it = 0; it < 2; it++) {
                    union { unsigned u[4]; bf16x8 v; } av;
#pragma unroll
                    for (int j = 0; j < 4; j++)
                        av.u[j] = __hip_atomic_load(hrow + it * 16 + j,
                                                    __ATOMIC_RELAXED, __HIP_MEMORY_SCOPE_AGENT);
                    accA[mh][0] = __builtin_amdgcn_mfma_f32_16x16x32_bf16(av.v, bh[0][it], accA[mh][0], 0, 0, 0);
                    accA[mh][1] = __builtin_amdgcn_mfma_f32_16x16x32_bf16(av.v, bh[1][it], accA[mh][1], 0, 0, 0);
                }
            }
        }
        // ---- write partials to LDS; pc = c ^ (q*8) ^ ((row&1)*4): <=2-way ----
        {
            float* slab = part + w * 1024;
#pragma unroll
            for (int mh = 0; mh < 2; mh++)
#pragma unroll
                for (int gp = 0; gp < 2; gp++)
#pragma unroll
                    for (int rr = 0; rr < 4; rr++) {
                        const int row = mh * 16 + q * 4 + rr;
                        const int pc = (gp * 16 + r) ^ (q * 8) ^ ((rr & 1) * 4);
                        slab[row * 32 + pc] = accA[mh][gp][rr];
                    }
        }
#pragma unroll
        for (int mh = 0; mh < 2; mh++) { accA[mh][0] = accB[mh][0]; accA[mh][1] = accB[mh][1]; }
        __syncthreads();

        // ---- cell update ----
        float hcar_r = 0.f, mt_r = 0.f;
        if (tid < 256) {
            float pf = b0, pi = b1, po = b2, pg = b3;
            const int rowbase = un * 32;
#pragma unroll
            for (int ww = 0; ww < 16; ww++) {
                const float* rowp = part + ww * 1024 + rowbase;
                pf += rowp[(0  + uc) ^ rswz];
                pi += rowp[(8  + uc) ^ rswz];
                po += rowp[(16 + uc) ^ rswz];
                pg += rowp[(24 + uc) ^ rswz];
            }
            const float f  = 1.f / (1.f + expf(-pf));
            const float i  = 1.f / (1.f + expf(-pi));
            const float o  = 1.f / (1.f + expf(-po));
            const float ct = tanhf(pg);
            creg = f * creg + i * ct;                 // c updated regardless of mask
            const float hnew = o * tanhf(creg);
            const float mt = mask[un * S_LEN + s_idx];
            const float hcar = (mt == 0.f) ? hreg : hnew;
            hreg = hcar;
            hcar_r = hcar; mt_r = mt;
            // publish h(t+1): pack col-pair, sc1 write-through store
            union { bf16 b; unsigned short u; } cv;
            cv.b = (bf16)hcar;
            const unsigned mine = cv.u;
            const unsigned other = (unsigned)__shfl_xor((int)mine, 1);
            if ((uc & 1) == 0) {
                unsigned* dst = hbuf + ((size_t)(((t + 1) & 1) * 2 + dir) * NBATCH + un) * 512
                              + ((col0 + uc) >> 1);
                __hip_atomic_store(dst, mine | (other << 16),
                                   __ATOMIC_RELAXED, __HIP_MEMORY_SCOPE_AGENT);
            }
        }
        __syncthreads();   // s_waitcnt vmcnt(0): h stores acked at L3 before flag
        if (tid == 0)
            __hip_atomic_store(&flags[bi * 16], (unsigned)(t + 1),
                               __ATOMIC_RELAXED, __HIP_MEMORY_SCOPE_AGENT);
        // ---- out stores off the critical path (cached, flushed at kernel end) ----
        if (tid < 256) {
            out[((size_t)(un * S_LEN + s_idx)) * 2048 + dir * 1024 + col0 + uc] = hcar_r * mt_r;
            if (t == S_LEN - 1)
                out[(size_t)NBATCH * S_LEN * 2048 + un * 2048 + dir * 1024 + col0 + uc] = hcar_r;
        }
    }
}

// ---------------------------------------------------------------------------
// Workspace layout (bytes), total ~48.3 MB:
//   [0,          16777216)  xT    bf16 [256 s][32 n][1024 d]
//   [16777216,   33554432)  wihT  bf16 [8 g][1024 h][1024 d]
//   [33554432,   50331648)  whhT  bf16 [8 g][1024 h][1024 k]
//   [50331648,   50593792)  hbuf  bf16 [2 parity][2 dir][32][1024] (u32 access)
//   [50593792,   50610176)  flags u32  [256] stride 16
// ---------------------------------------------------------------------------
extern "C" void kernel_launch(void* const* d_in, const int* in_sizes, int n_in,
                              void* d_out, int out_size, void* d_ws, size_t ws_size,
                              hipStream_t stream) {
    const float* x    = (const float*)d_in[0];
    const float* mask = (const float*)d_in[1];
    const float* wih  = (const float*)d_in[2];
    const float* whh  = (const float*)d_in[3];
    const float* bias = (const float*)d_in[4];
    float* out = (float*)d_out;

    char* ws = (char*)d_ws;
    bf16*     xT    = (bf16*)(ws);
    bf16*     wihT  = (bf16*)(ws + 16777216);
    bf16*     whhT  = (bf16*)(ws + 33554432);
    unsigned* hbuf  = (unsigned*)(ws + 50331648);
    unsigned* flags = (unsigned*)(ws + 50593792);

    // zero h (both parities) and barrier flags (ws is re-poisoned every call)
    hipMemsetAsync(ws + 50331648, 0, 262144 + 16384, stream);

    convert_x<<<NBATCH * S_LEN, 256, 0, stream>>>(x, xT);
    dim3 tb(32, 8);
    convert_transpose_1024<<<dim3(32, 32, 8), tb, 0, stream>>>(wih, wihT);
    convert_transpose_1024<<<dim3(32, 32, 8), tb, 0, stream>>>(whh, whhT);

    lstm_persistent<<<NBLK, 1024, 0, stream>>>(xT, wihT, whhT, mask, bias,
                                               hbuf, flags, out);
}

// Round 7
// 2597.034 us; speedup vs baseline: 2.9525x; 1.1743x over previous
//
#include <hip/hip_runtime.h>
#include <hip/hip_bf16.h>

using bf16 = __hip_bfloat16;
using bf16x8 = __attribute__((ext_vector_type(8))) short;   // 8 bf16 = 4 VGPRs
using f32x4  = __attribute__((ext_vector_type(4))) float;
typedef unsigned long long u64;

#define S_LEN 256
#define NBATCH 32
#define HDIM 1024
#define NBLK 256
#define SENT 0x7F7F7F7Fu   // packed bf16 pair 0x7F7F = 3.3e38: impossible for |h|<1

// ---------------------------------------------------------------------------
// Convert x (f32, [n][s][d]) -> xT (bf16, [s][n][d]).
// ---------------------------------------------------------------------------
__global__ __launch_bounds__(256) void convert_x(const float* __restrict__ x,
                                                 bf16* __restrict__ xT) {
    const int p = blockIdx.x;          // p = n*256 + s
    const int n = p >> 8;
    const int s = p & 255;
    const float* src = x + (size_t)p * 1024;
    bf16* dst = xT + (size_t)(s * NBATCH + n) * 1024;
#pragma unroll
    for (int j = 0; j < 4; j++) {
        const int d = threadIdx.x + j * 256;
        dst[d] = (bf16)src[d];
    }
}

// ---------------------------------------------------------------------------
// Convert + transpose: 8 matrices of 1024x1024, f32 in, bf16 out,
// out[g][c][r] = in[g][r][c]
// ---------------------------------------------------------------------------
__global__ __launch_bounds__(256) void convert_transpose_1024(const float* __restrict__ in,
                                                              bf16* __restrict__ out) {
    __shared__ float t[32][33];
    const int g  = blockIdx.z;
    const float* A = in  + (size_t)g * 1024 * 1024;
    bf16*        B = out + (size_t)g * 1024 * 1024;
    const int c0 = blockIdx.x * 32;
    const int r0 = blockIdx.y * 32;
    const int tx = threadIdx.x, ty = threadIdx.y;   // (32, 8)
#pragma unroll
    for (int j = 0; j < 32; j += 8)
        t[ty + j][tx] = A[(size_t)(r0 + ty + j) * 1024 + c0 + tx];
    __syncthreads();
#pragma unroll
    for (int j = 0; j < 32; j += 8)
        B[(size_t)(c0 + ty + j) * 1024 + r0 + tx] = (bf16)t[tx][ty + j];
}

// ---------------------------------------------------------------------------
// Persistent BiLSTM — flag-free, self-synchronizing via data sentinels.
// 256 blocks x 1024 thr, 1 block/CU. Block = (dir, 8 cols). Wave w owns
// K-slice [w*64,(w+1)*64) of Wih+Whh (pinned in regs).
// hbuf is a 4-deep ring [slot = t&3]; stale entries hold SENT. Per step:
//   issue h(t) loads (slot t&3, sc1 bypass) -> overlap x(t+1) MFMAs ->
//   retry stale u64s -> h MFMAs into held x(t) partials -> LDS (swizzle
//   f(row,col)=col^((row&7)*4): exactly 2-way both ways) -> update threads
//   (c,h in regs): reset slot t+2 to SENT, cell math, publish h(t+1) as
//   packed-u32 sc1 stores (the publish IS the readiness signal).
// No flags, no grid barrier, no fences, no wbl2.
// ---------------------------------------------------------------------------
__global__ __launch_bounds__(1024) void lstm_persistent(
        const bf16* __restrict__ xT,
        const bf16* __restrict__ wihT,
        const bf16* __restrict__ whhT,
        const float* __restrict__ mask,
        const float* __restrict__ bias,
        unsigned* __restrict__ hbuf,    // [4 slot][2 dir][32 n][512] u32 (bf16 pairs)
        float* __restrict__ out) {
    __shared__ float part[16 * 1024];   // 64 KB: slab w = [32 rows][32 cols] swizzled

    const int bi   = blockIdx.x;
    const int dir  = bi >> 7;
    const int col0 = (bi & 127) << 3;
    const int tid  = threadIdx.x;
    const int w    = tid >> 6;
    const int lane = tid & 63;
    const int r    = lane & 15;
    const int q    = lane >> 4;
    const int kbase = w * 64 + q * 8;   // this wave's K-slice origin (+quad)

    // ---- pin weights: B-frags for both matrices, both gate-pairs ----
    bf16x8 bx[2][2], bh[2][2];
#pragma unroll
    for (int gp = 0; gp < 2; gp++) {
        const int gate = gp * 2 + (r >> 3);
        const size_t rowoff = ((size_t)((dir * 4 + gate) * 1024 + col0 + (r & 7))) * 1024 + kbase;
#pragma unroll
        for (int it = 0; it < 2; it++) {
            bx[gp][it] = *(const bf16x8*)(wihT + rowoff + it * 32);
            bh[gp][it] = *(const bf16x8*)(whhT + rowoff + it * 32);
        }
    }

    // ---- update-thread state (tid<256 owns (n = tid>>3, c = tid&7)) ----
    const int un = tid >> 3;
    const int uc = tid & 7;
    float creg = 0.f, hreg = 0.f;
    float b0 = 0.f, b1 = 0.f, b2 = 0.f, b3 = 0.f;
    if (tid < 256) {
        const int gb = (dir * 4) * 1024 + col0 + uc;
        b0 = bias[gb];
        b1 = bias[gb + 1024];
        b2 = bias[gb + 2048];
        b3 = bias[gb + 3072];
    }
    const int rx = (un & 7) * 4;        // update-read swizzle

    const f32x4 vzero = {0.f, 0.f, 0.f, 0.f};
    f32x4 accA[2][2], accB[2][2];
#pragma unroll
    for (int mh = 0; mh < 2; mh++) { accB[mh][0] = vzero; accB[mh][1] = vzero; }

    // ---- prologue: accA = x(0) partials ----
    {
        const int s_id = dir ? (S_LEN - 1) : 0;
        const bf16* Ax = xT + (size_t)s_id * NBATCH * HDIM + kbase;
#pragma unroll
        for (int mh = 0; mh < 2; mh++) {
            accA[mh][0] = vzero; accA[mh][1] = vzero;
#pragma unroll
            for (int it = 0; it < 2; it++) {
                bf16x8 a = *(const bf16x8*)(Ax + (size_t)(mh * 16 + r) * HDIM + it * 32);
                accA[mh][0] = __builtin_amdgcn_mfma_f32_16x16x32_bf16(a, bx[0][it], accA[mh][0], 0, 0, 0);
                accA[mh][1] = __builtin_amdgcn_mfma_f32_16x16x32_bf16(a, bx[1][it], accA[mh][1], 0, 0, 0);
            }
        }
    }

    for (int t = 0; t < S_LEN; ++t) {
        const int s_idx = dir ? (S_LEN - 1 - t) : t;

        // ---- issue h(t) loads early (slot t&3); retried below if stale ----
        const u64* Hp = (const u64*)hbuf
                      + ((size_t)((t & 3) * 2 + dir) * NBATCH) * 256 + (kbase >> 2);
        u64 hv[2][2][2];
#pragma unroll
        for (int mh = 0; mh < 2; mh++)
#pragma unroll
            for (int it = 0; it < 2; it++)
#pragma unroll
                for (int j = 0; j < 2; j++)
                    hv[mh][it][j] = __hip_atomic_load(
                        Hp + (size_t)(mh * 16 + r) * 256 + it * 8 + j,
                        __ATOMIC_RELAXED, __HIP_MEMORY_SCOPE_AGENT);

        // ---- overlap: x(t+1) -> accB (no cross-block dependency) ----
        if (t + 1 < S_LEN) {
            const int s_id = dir ? (S_LEN - 2 - t) : (t + 1);
            const bf16* Ax = xT + (size_t)s_id * NBATCH * HDIM + kbase;
#pragma unroll
            for (int mh = 0; mh < 2; mh++) {
                accB[mh][0] = vzero; accB[mh][1] = vzero;
#pragma unroll
                for (int it = 0; it < 2; it++) {
                    bf16x8 a = *(const bf16x8*)(Ax + (size_t)(mh * 16 + r) * HDIM + it * 32);
                    accB[mh][0] = __builtin_amdgcn_mfma_f32_16x16x32_bf16(a, bx[0][it], accB[mh][0], 0, 0, 0);
                    accB[mh][1] = __builtin_amdgcn_mfma_f32_16x16x32_bf16(a, bx[1][it], accB[mh][1], 0, 0, 0);
                }
            }
        }

        // ---- retry stale h u64s (sentinel in either 32-bit half) ----
#pragma unroll
        for (int mh = 0; mh < 2; mh++)
#pragma unroll
            for (int it = 0; it < 2; it++)
#pragma unroll
                for (int j = 0; j < 2; j++) {
                    u64 v = hv[mh][it][j];
                    const u64* p = Hp + (size_t)(mh * 16 + r) * 256 + it * 8 + j;
                    int guard = 0;
                    while ((unsigned)v == SENT || (unsigned)(v >> 32) == SENT) {
                        if (++guard > (1 << 20)) break;   // safety valve
                        v = __hip_atomic_load(p, __ATOMIC_RELAXED, __HIP_MEMORY_SCOPE_AGENT);
                    }
                    hv[mh][it][j] = v;
                }

        // ---- h(t) @ Whh accumulated into accA ----
#pragma unroll
        for (int mh = 0; mh < 2; mh++)
#pragma unroll
            for (int it = 0; it < 2; it++) {
                union { u64 qv[2]; bf16x8 v; } av;
                av.qv[0] = hv[mh][it][0];
                av.qv[1] = hv[mh][it][1];
                accA[mh][0] = __builtin_amdgcn_mfma_f32_16x16x32_bf16(av.v, bh[0][it], accA[mh][0], 0, 0, 0);
                accA[mh][1] = __builtin_amdgcn_mfma_f32_16x16x32_bf16(av.v, bh[1][it], accA[mh][1], 0, 0, 0);
            }

        // ---- partials -> LDS; f(row,col) = col ^ ((row&7)*4): 2-way exact ----
        {
            float* slab = part + w * 1024;
#pragma unroll
            for (int mh = 0; mh < 2; mh++)
#pragma unroll
                for (int gp = 0; gp < 2; gp++)
#pragma unroll
                    for (int rr = 0; rr < 4; rr++) {
                        const int row = mh * 16 + q * 4 + rr;
                        const int pc = (gp * 16 + r) ^ ((row & 7) * 4);
                        slab[row * 32 + pc] = accA[mh][gp][rr];
                    }
        }
#pragma unroll
        for (int mh = 0; mh < 2; mh++) { accA[mh][0] = accB[mh][0]; accA[mh][1] = accB[mh][1]; }
        __syncthreads();

        // ---- cell update ----
        float hcar_r = 0.f, mt_r = 0.f;
        if (tid < 256) {
            // reset slot t+2 to sentinel first: >=1 update-math latency +
            // a vmcnt-drained barrier separate this from that slot's payload
            if ((uc & 1) == 0) {
                unsigned* rdst = hbuf
                    + ((size_t)(((t + 2) & 3) * 2 + dir) * NBATCH + un) * 512
                    + ((col0 + uc) >> 1);
                __hip_atomic_store(rdst, SENT, __ATOMIC_RELAXED, __HIP_MEMORY_SCOPE_AGENT);
            }
            float pf = b0, pi = b1, po = b2, pg = b3;
            const int rowbase = un * 32;
#pragma unroll
            for (int ww = 0; ww < 16; ww++) {
                const float* rowp = part + ww * 1024 + rowbase;
                pf += rowp[(0  + uc) ^ rx];
                pi += rowp[(8  + uc) ^ rx];
                po += rowp[(16 + uc) ^ rx];
                pg += rowp[(24 + uc) ^ rx];
            }
            const float f  = 1.f / (1.f + expf(-pf));
            const float i  = 1.f / (1.f + expf(-pi));
            const float o  = 1.f / (1.f + expf(-po));
            const float ct = tanhf(pg);
            creg = f * creg + i * ct;                 // c updated regardless of mask
            const float hnew = o * tanhf(creg);
            const float mt = mask[un * S_LEN + s_idx];
            const float hcar = (mt == 0.f) ? hreg : hnew;
            hreg = hcar;
            hcar_r = hcar; mt_r = mt;
            // publish h(t+1) into slot (t+1)&3 — this IS the readiness signal
            union { bf16 b; unsigned short u; } cv;
            cv.b = (bf16)hcar;
            const unsigned mine = cv.u;
            const unsigned other = (unsigned)__shfl_xor((int)mine, 1);
            if ((uc & 1) == 0) {
                unsigned* dst = hbuf
                    + ((size_t)(((t + 1) & 3) * 2 + dir) * NBATCH + un) * 512
                    + ((col0 + uc) >> 1);
                __hip_atomic_store(dst, mine | (other << 16),
                                   __ATOMIC_RELAXED, __HIP_MEMORY_SCOPE_AGENT);
            }
            // out stores: cached, flushed at kernel end, nobody reads them
            out[((size_t)(un * S_LEN + s_idx)) * 2048 + dir * 1024 + col0 + uc] = hcar_r * mt_r;
            if (t == S_LEN - 1)
                out[(size_t)NBATCH * S_LEN * 2048 + un * 2048 + dir * 1024 + col0 + uc] = hcar_r;
        }
        __syncthreads();   // part[] consumed; also vmcnt-drains reset+publish
    }
}

// ---------------------------------------------------------------------------
// Workspace layout (bytes), total ~50.9 MB:
//   [0,          16777216)  xT    bf16 [256 s][32 n][1024 d]
//   [16777216,   33554432)  wihT  bf16 [8 g][1024 h][1024 d]
//   [33554432,   50331648)  whhT  bf16 [8 g][1024 h][1024 k]
//   [50331648,   50855936)  hbuf  bf16 [4 slot][2 dir][32][1024] (u32 access)
//                           slot 0 zeroed (h(0)=0), slots 1-3 = 0x7F sentinel
// ---------------------------------------------------------------------------
extern "C" void kernel_launch(void* const* d_in, const int* in_sizes, int n_in,
                              void* d_out, int out_size, void* d_ws, size_t ws_size,
                              hipStream_t stream) {
    const float* x    = (const float*)d_in[0];
    const float* mask = (const float*)d_in[1];
    const float* wih  = (const float*)d_in[2];
    const float* whh  = (const float*)d_in[3];
    const float* bias = (const float*)d_in[4];
    float* out = (float*)d_out;

    char* ws = (char*)d_ws;
    bf16*     xT    = (bf16*)(ws);
    bf16*     wihT  = (bf16*)(ws + 16777216);
    bf16*     whhT  = (bf16*)(ws + 33554432);
    unsigned* hbuf  = (unsigned*)(ws + 50331648);

    // slot 0 = zeros (valid h(0)); slots 1-3 = sentinel bytes
    hipMemsetAsync(ws + 50331648, 0x00, 131072, stream);
    hipMemsetAsync(ws + 50331648 + 131072, 0x7F, 393216, stream);

    convert_x<<<NBATCH * S_LEN, 256, 0, stream>>>(x, xT);
    dim3 tb(32, 8);
    convert_transpose_1024<<<dim3(32, 32, 8), tb, 0, stream>>>(wih, wihT);
    convert_transpose_1024<<<dim3(32, 32, 8), tb, 0, stream>>>(whh, whhT);

    lstm_persistent<<<NBLK, 1024, 0, stream>>>(xT, wihT, whhT, mask, bias,
                                               hbuf, out);
}

// Round 8
// 2418.485 us; speedup vs baseline: 3.1705x; 1.0738x over previous
//
#include <hip/hip_runtime.h>
#include <hip/hip_bf16.h>

using bf16 = __hip_bfloat16;
using bf16x8 = __attribute__((ext_vector_type(8))) short;   // 8 bf16 = 4 VGPRs
using f32x4  = __attribute__((ext_vector_type(4))) float;
typedef unsigned long long u64;

#define S_LEN 256
#define NBATCH 32
#define HDIM 1024
#define NBLK 256
#define SENT 0x7F7F7F7Fu   // packed bf16 pair 0x7F7F = 3.3e38: impossible for |h|<1
#define SENT64 0x7F7F7F7F7F7F7F7Full

__device__ __forceinline__ float fast_sig(float x) {
    return __builtin_amdgcn_rcpf(1.f + __expf(-x));
}
__device__ __forceinline__ float fast_tanh(float x) {
    return 1.f - 2.f * __builtin_amdgcn_rcpf(1.f + __expf(2.f * x));
}
__device__ __forceinline__ bool is_stale(u64 v) {
    return ((unsigned)v == SENT) || ((unsigned)(v >> 32) == SENT);
}

// ---------------------------------------------------------------------------
// Convert x (f32, [n][s][d]) -> xT (bf16, [s][n][d]).
// ---------------------------------------------------------------------------
__global__ __launch_bounds__(256) void convert_x(const float* __restrict__ x,
                                                 bf16* __restrict__ xT) {
    const int p = blockIdx.x;          // p = n*256 + s
    const int n = p >> 8;
    const int s = p & 255;
    const float* src = x + (size_t)p * 1024;
    bf16* dst = xT + (size_t)(s * NBATCH + n) * 1024;
#pragma unroll
    for (int j = 0; j < 4; j++) {
        const int d = threadIdx.x + j * 256;
        dst[d] = (bf16)src[d];
    }
}

// ---------------------------------------------------------------------------
// Convert + transpose: 8 matrices of 1024x1024, f32 in, bf16 out,
// out[g][c][r] = in[g][r][c]
// ---------------------------------------------------------------------------
__global__ __launch_bounds__(256) void convert_transpose_1024(const float* __restrict__ in,
                                                              bf16* __restrict__ out) {
    __shared__ float t[32][33];
    const int g  = blockIdx.z;
    const float* A = in  + (size_t)g * 1024 * 1024;
    bf16*        B = out + (size_t)g * 1024 * 1024;
    const int c0 = blockIdx.x * 32;
    const int r0 = blockIdx.y * 32;
    const int tx = threadIdx.x, ty = threadIdx.y;   // (32, 8)
#pragma unroll
    for (int j = 0; j < 32; j += 8)
        t[ty + j][tx] = A[(size_t)(r0 + ty + j) * 1024 + c0 + tx];
    __syncthreads();
#pragma unroll
    for (int j = 0; j < 32; j += 8)
        B[(size_t)(c0 + ty + j) * 1024 + r0 + tx] = (bf16)t[tx][ty + j];
}

// ---------------------------------------------------------------------------
// Persistent BiLSTM — flag-free, self-synchronizing via data sentinels.
// 256 blocks x 1024 thr, 1 block/CU. Block = (dir, 8 cols). Wave w owns
// K-slice [w*64,(w+1)*64) of Wih+Whh (pinned in regs).
// hbuf = 4-deep ring [slot = t&3]; stale entries hold SENT. Per step:
//   issue h(t) loads (sc1 bypass) -> overlap x(t+1) MFMAs -> BATCHED retry
//   sweeps (all stale u64s reloaded in parallel, one waitcnt per sweep) ->
//   h MFMAs into held x(t) partials -> LDS (swizzle col^((row&7)*4), 2-way
//   both ways) -> update threads (c,h in regs, native exp/rcp math): reset
//   slot t+2 to SENT (u64), cell math, publish h(t+1) as packed u64 sc1
//   stores (the publish IS the readiness signal).
// ---------------------------------------------------------------------------
__global__ __launch_bounds__(1024) void lstm_persistent(
        const bf16* __restrict__ xT,
        const bf16* __restrict__ wihT,
        const bf16* __restrict__ whhT,
        const float* __restrict__ mask,
        const float* __restrict__ bias,
        unsigned* __restrict__ hbuf,    // [4 slot][2 dir][32 n][512] u32 (bf16 pairs)
        float* __restrict__ out) {
    __shared__ float part[16 * 1024];   // 64 KB: slab w = [32 rows][32 cols] swizzled

    const int bi   = blockIdx.x;
    const int dir  = bi >> 7;
    const int col0 = (bi & 127) << 3;
    const int tid  = threadIdx.x;
    const int w    = tid >> 6;
    const int lane = tid & 63;
    const int r    = lane & 15;
    const int q    = lane >> 4;
    const int kbase = w * 64 + q * 8;   // this wave's K-slice origin (+quad)

    // ---- pin weights: B-frags for both matrices, both gate-pairs ----
    bf16x8 bx[2][2], bh[2][2];
#pragma unroll
    for (int gp = 0; gp < 2; gp++) {
        const int gate = gp * 2 + (r >> 3);
        const size_t rowoff = ((size_t)((dir * 4 + gate) * 1024 + col0 + (r & 7))) * 1024 + kbase;
#pragma unroll
        for (int it = 0; it < 2; it++) {
            bx[gp][it] = *(const bf16x8*)(wihT + rowoff + it * 32);
            bh[gp][it] = *(const bf16x8*)(whhT + rowoff + it * 32);
        }
    }

    // ---- update-thread state (tid<256 owns (n = tid>>3, c = tid&7)) ----
    const int un = tid >> 3;
    const int uc = tid & 7;
    float creg = 0.f, hreg = 0.f;
    float b0 = 0.f, b1 = 0.f, b2 = 0.f, b3 = 0.f;
    if (tid < 256) {
        const int gb = (dir * 4) * 1024 + col0 + uc;
        b0 = bias[gb];
        b1 = bias[gb + 1024];
        b2 = bias[gb + 2048];
        b3 = bias[gb + 3072];
    }
    const int rx = (un & 7) * 4;        // update-read swizzle

    const f32x4 vzero = {0.f, 0.f, 0.f, 0.f};
    f32x4 accA[2][2], accB[2][2];
#pragma unroll
    for (int mh = 0; mh < 2; mh++) { accB[mh][0] = vzero; accB[mh][1] = vzero; }

    // ---- prologue: accA = x(0) partials ----
    {
        const int s_id = dir ? (S_LEN - 1) : 0;
        const bf16* Ax = xT + (size_t)s_id * NBATCH * HDIM + kbase;
#pragma unroll
        for (int mh = 0; mh < 2; mh++) {
            accA[mh][0] = vzero; accA[mh][1] = vzero;
#pragma unroll
            for (int it = 0; it < 2; it++) {
                bf16x8 a = *(const bf16x8*)(Ax + (size_t)(mh * 16 + r) * HDIM + it * 32);
                accA[mh][0] = __builtin_amdgcn_mfma_f32_16x16x32_bf16(a, bx[0][it], accA[mh][0], 0, 0, 0);
                accA[mh][1] = __builtin_amdgcn_mfma_f32_16x16x32_bf16(a, bx[1][it], accA[mh][1], 0, 0, 0);
            }
        }
    }

    for (int t = 0; t < S_LEN; ++t) {
        const int s_idx = dir ? (S_LEN - 1 - t) : t;

        // ---- issue h(t) loads early (slot t&3); swept below if stale ----
        const u64* Hp = (const u64*)hbuf
                      + ((size_t)((t & 3) * 2 + dir) * NBATCH) * 256 + (kbase >> 2);
        u64 hv[2][2][2];
#pragma unroll
        for (int mh = 0; mh < 2; mh++)
#pragma unroll
            for (int it = 0; it < 2; it++)
#pragma unroll
                for (int j = 0; j < 2; j++)
                    hv[mh][it][j] = __hip_atomic_load(
                        Hp + (size_t)(mh * 16 + r) * 256 + it * 8 + j,
                        __ATOMIC_RELAXED, __HIP_MEMORY_SCOPE_AGENT);

        // ---- overlap: x(t+1) -> accB (no cross-block dependency) ----
        if (t + 1 < S_LEN) {
            const int s_id = dir ? (S_LEN - 2 - t) : (t + 1);
            const bf16* Ax = xT + (size_t)s_id * NBATCH * HDIM + kbase;
#pragma unroll
            for (int mh = 0; mh < 2; mh++) {
                accB[mh][0] = vzero; accB[mh][1] = vzero;
#pragma unroll
                for (int it = 0; it < 2; it++) {
                    bf16x8 a = *(const bf16x8*)(Ax + (size_t)(mh * 16 + r) * HDIM + it * 32);
                    accB[mh][0] = __builtin_amdgcn_mfma_f32_16x16x32_bf16(a, bx[0][it], accB[mh][0], 0, 0, 0);
                    accB[mh][1] = __builtin_amdgcn_mfma_f32_16x16x32_bf16(a, bx[1][it], accB[mh][1], 0, 0, 0);
                }
            }
        }

        // ---- BATCHED retry sweeps: reload all stale u64s in parallel ----
        {
            int guard = 0;
            while (true) {
                bool stale = false;
#pragma unroll
                for (int mh = 0; mh < 2; mh++)
#pragma unroll
                    for (int it = 0; it < 2; it++)
#pragma unroll
                        for (int j = 0; j < 2; j++)
                            stale |= is_stale(hv[mh][it][j]);
                if (!stale || ++guard > 8192) break;
#pragma unroll
                for (int mh = 0; mh < 2; mh++)
#pragma unroll
                    for (int it = 0; it < 2; it++)
#pragma unroll
                        for (int j = 0; j < 2; j++)
                            if (is_stale(hv[mh][it][j]))
                                hv[mh][it][j] = __hip_atomic_load(
                                    Hp + (size_t)(mh * 16 + r) * 256 + it * 8 + j,
                                    __ATOMIC_RELAXED, __HIP_MEMORY_SCOPE_AGENT);
            }
        }

        // ---- h(t) @ Whh accumulated into accA ----
#pragma unroll
        for (int mh = 0; mh < 2; mh++)
#pragma unroll
            for (int it = 0; it < 2; it++) {
                union { u64 qv[2]; bf16x8 v; } av;
                av.qv[0] = hv[mh][it][0];
                av.qv[1] = hv[mh][it][1];
                accA[mh][0] = __builtin_amdgcn_mfma_f32_16x16x32_bf16(av.v, bh[0][it], accA[mh][0], 0, 0, 0);
                accA[mh][1] = __builtin_amdgcn_mfma_f32_16x16x32_bf16(av.v, bh[1][it], accA[mh][1], 0, 0, 0);
            }

        // ---- partials -> LDS; f(row,col) = col ^ ((row&7)*4): 2-way exact ----
        {
            float* slab = part + w * 1024;
#pragma unroll
            for (int mh = 0; mh < 2; mh++)
#pragma unroll
                for (int gp = 0; gp < 2; gp++)
#pragma unroll
                    for (int rr = 0; rr < 4; rr++) {
                        const int row = mh * 16 + q * 4 + rr;
                        const int pc = (gp * 16 + r) ^ ((row & 7) * 4);
                        slab[row * 32 + pc] = accA[mh][gp][rr];
                    }
        }
#pragma unroll
        for (int mh = 0; mh < 2; mh++) { accA[mh][0] = accB[mh][0]; accA[mh][1] = accB[mh][1]; }
        __syncthreads();

        // ---- cell update ----
        if (tid < 256) {
            // reset slot t+2 to sentinel (u64, 4 cols/lane via shfl gather no-op:
            // constant value, lanes uc&3==0 store)
            if ((uc & 3) == 0) {
                u64* rdst = (u64*)hbuf
                    + ((size_t)(((t + 2) & 3) * 2 + dir) * NBATCH + un) * 256
                    + ((col0 + uc) >> 2);
                __hip_atomic_store(rdst, SENT64, __ATOMIC_RELAXED, __HIP_MEMORY_SCOPE_AGENT);
            }
            float pf = b0, pi = b1, po = b2, pg = b3;
            const int rowbase = un * 32;
#pragma unroll
            for (int ww = 0; ww < 16; ww++) {
                const float* rowp = part + ww * 1024 + rowbase;
                pf += rowp[(0  + uc) ^ rx];
                pi += rowp[(8  + uc) ^ rx];
                po += rowp[(16 + uc) ^ rx];
                pg += rowp[(24 + uc) ^ rx];
            }
            const float f  = fast_sig(pf);
            const float i  = fast_sig(pi);
            const float o  = fast_sig(po);
            const float ct = fast_tanh(pg);
            creg = f * creg + i * ct;                 // c updated regardless of mask
            const float hnew = o * fast_tanh(creg);
            const float mt = mask[un * S_LEN + s_idx];
            const float hcar = (mt == 0.f) ? hreg : hnew;
            hreg = hcar;
            // publish h(t+1): gather 4 cols -> u64, lanes uc&3==0 store
            union { bf16 b; unsigned short u; } cv;
            cv.b = (bf16)hcar;
            const unsigned mine  = cv.u;
            const unsigned other = (unsigned)__shfl_xor((int)mine, 1);
            const unsigned pair  = mine | (other << 16);           // cols uc,uc+1 (even lanes)
            const unsigned pair2 = (unsigned)__shfl_xor((int)pair, 2);
            if ((uc & 3) == 0) {
                u64* dst = (u64*)hbuf
                    + ((size_t)(((t + 1) & 3) * 2 + dir) * NBATCH + un) * 256
                    + ((col0 + uc) >> 2);
                __hip_atomic_store(dst, (u64)pair | ((u64)pair2 << 32),
                                   __ATOMIC_RELAXED, __HIP_MEMORY_SCOPE_AGENT);
            }
            // out stores: cached, flushed at kernel end, nobody reads them
            out[((size_t)(un * S_LEN + s_idx)) * 2048 + dir * 1024 + col0 + uc] = hcar * mt;
            if (t == S_LEN - 1)
                out[(size_t)NBATCH * S_LEN * 2048 + un * 2048 + dir * 1024 + col0 + uc] = hcar;
        }
        __syncthreads();   // part[] consumed; also vmcnt-drains reset+publish
    }
}

// ---------------------------------------------------------------------------
// Workspace layout (bytes), total ~50.9 MB:
//   [0,          16777216)  xT    bf16 [256 s][32 n][1024 d]
//   [16777216,   33554432)  wihT  bf16 [8 g][1024 h][1024 d]
//   [33554432,   50331648)  whhT  bf16 [8 g][1024 h][1024 k]
//   [50331648,   50855936)  hbuf  bf16 [4 slot][2 dir][32][1024] (u32 access)
//                           slot 0 zeroed (h(0)=0), slots 1-3 = 0x7F sentinel
// ---------------------------------------------------------------------------
extern "C" void kernel_launch(void* const* d_in, const int* in_sizes, int n_in,
                              void* d_out, int out_size, void* d_ws, size_t ws_size,
                              hipStream_t stream) {
    const float* x    = (const float*)d_in[0];
    const float* mask = (const float*)d_in[1];
    const float* wih  = (const float*)d_in[2];
    const float* whh  = (const float*)d_in[3];
    const float* bias = (const float*)d_in[4];
    float* out = (float*)d_out;

    char* ws = (char*)d_ws;
    bf16*     xT    = (bf16*)(ws);
    bf16*     wihT  = (bf16*)(ws + 16777216);
    bf16*     whhT  = (bf16*)(ws + 33554432);
    unsigned* hbuf  = (unsigned*)(ws + 50331648);

    // slot 0 = zeros (valid h(0)); slots 1-3 = sentinel bytes
    hipMemsetAsync(ws + 50331648, 0x00, 131072, stream);
    hipMemsetAsync(ws + 50331648 + 131072, 0x7F, 393216, stream);

    convert_x<<<NBATCH * S_LEN, 256, 0, stream>>>(x, xT);
    dim3 tb(32, 8);
    convert_transpose_1024<<<dim3(32, 32, 8), tb, 0, stream>>>(wih, wihT);
    convert_transpose_1024<<<dim3(32, 32, 8), tb, 0, stream>>>(whh, whhT);

    lstm_persistent<<<NBLK, 1024, 0, stream>>>(xT, wihT, whhT, mask, bias,
                                               hbuf, out);
}